// Round 11
// baseline (335.936 us; speedup 1.0000x reference)
//
#include <hip/hip_runtime.h>
#include <math.h>

// ---------------------------------------------------------------------------
// B=32 queries [B,512] fp32 vs N=20000 keys [N,512] fp32.
// scores = Q K^T / sqrt(512); softmax over N; top-8; gather values rows.
// Output = [B*8 weights f32] ++ [B*8 * 10240 values f32].
//
// R11: 2 kernels.
//  K1 score_part: R8-proven verbatim (64 keys/block, MFMA, in-block partials).
//  K2 merge_gather: 32 producer blocks (R8 row_merge verbatim -> tidx +
//     weights -> RELEASE flag per row) + 1024 consumer blocks (acquire-spin
//     on own row's flag -> gather quarter segment). 1056 blocks co-resident
//     (4.1/CU < 8 capacity) -> no deadlock, no dispatch-order assumption.
//     Removes the K2->K3 kernel edge without R9's x32 redundant merge cost.
// ---------------------------------------------------------------------------

#define TOPK 8
#define DKD 512
#define NEG  -1.0e30f

typedef __attribute__((ext_vector_type(8))) short short8;
typedef __attribute__((ext_vector_type(4))) float f32x4;

__device__ inline unsigned short f2bf(float x) {
    unsigned int u = __float_as_uint(x);
    u = (u + 0x7fffu + ((u >> 16) & 1u)) >> 16;   // RNE to bf16
    return (unsigned short)u;
}

// comparator everywhere: value desc, index asc (matches lax.top_k ties)
__device__ inline void wave_argmax(float& v, int& i) {
    #pragma unroll
    for (int off = 1; off < 64; off <<= 1) {
        float ov = __shfl_xor(v, off);
        int   oi = __shfl_xor(i, off);
        if (ov > v || (ov == v && oi < i)) { v = ov; i = oi; }
    }
}

// sorted-desc top-8 insert (boolean network, strict > keeps earlier index on ties)
__device__ inline void top8_insert(float (&v)[8], int (&ji)[8], float x, int gi) {
    if (x > v[7]) {
        bool g[8];
        #pragma unroll
        for (int k = 0; k < 8; ++k) g[k] = (x > v[k]);
        #pragma unroll
        for (int k = 7; k >= 1; --k) {
            v[k]  = g[k] ? (g[k - 1] ? v[k - 1] : x)  : v[k];
            ji[k] = g[k] ? (g[k - 1] ? ji[k - 1] : gi) : ji[k];
        }
        v[0]  = g[0] ? x  : v[0];
        ji[0] = g[0] ? gi : ji[0];
    }
}

// ---- K1: MFMA scores (64 keys/block) + in-block per-row partials ----------
__global__ __launch_bounds__(256) void score_part_kernel(
    const float* __restrict__ q, const float* __restrict__ keys,
    float* __restrict__ pmg, float* __restrict__ psg,
    float* __restrict__ cvg, int* __restrict__ cig, int N, int NTB)
{
    const int tid  = threadIdx.x;
    const int lane = tid & 63;
    const int wid  = tid >> 6;
    const float scale = 0.04419417382415922f;   // 1/sqrt(512)

    __shared__ short qs[32][DKD + 8];   // bf16 q, +8 pad (2-way banks = free)
    __shared__ float S[32][65];         // scores tile, +1 pad

    // ---- P0: q -> bf16 into LDS (64KB read, 1x per block) ----
    #pragma unroll
    for (int i = 0; i < 16; ++i) {
        const int idx = i * 256 + tid;          // 0..4095 float4s
        const int row = idx >> 7;               // 128 float4 per row
        const int c4  = idx & 127;
        float4 v = *reinterpret_cast<const float4*>(&q[row * DKD + c4 * 4]);
        ushort4 h;
        h.x = f2bf(v.x); h.y = f2bf(v.y); h.z = f2bf(v.z); h.w = f2bf(v.w);
        *reinterpret_cast<ushort4*>(&qs[row][c4 * 4]) = h;
    }
    __syncthreads();

    // ---- P1: 16-key MFMA tile per wave ----
    {
        const int col = lane & 15;
        const int kg  = lane >> 4;
        const int n0  = blockIdx.x * 64 + wid * 16;

        f32x4 acc0 = {0.f, 0.f, 0.f, 0.f};
        f32x4 acc1 = {0.f, 0.f, 0.f, 0.f};

        int nrow = n0 + col;
        const bool valid = (nrow < N);
        if (!valid) nrow = N - 1;               // clamp loads
        const float* krow = keys + (size_t)nrow * DKD + kg * 8;
        const short* s0 = &qs[col][kg * 8];
        const short* s1 = &qs[col + 16][kg * 8];

        #pragma unroll 4
        for (int ks = 0; ks < 16; ++ks) {
            const int d = ks * 32;
            float4 ka = *reinterpret_cast<const float4*>(krow + d);
            float4 kb = *reinterpret_cast<const float4*>(krow + d + 4);
            short8 fh;
            fh[0] = (short)f2bf(ka.x); fh[1] = (short)f2bf(ka.y);
            fh[2] = (short)f2bf(ka.z); fh[3] = (short)f2bf(ka.w);
            fh[4] = (short)f2bf(kb.x); fh[5] = (short)f2bf(kb.y);
            fh[6] = (short)f2bf(kb.z); fh[7] = (short)f2bf(kb.w);
            short8 a0 = *reinterpret_cast<const short8*>(s0 + d);
            short8 a1 = *reinterpret_cast<const short8*>(s1 + d);
            acc0 = __builtin_amdgcn_mfma_f32_16x16x32_bf16(a0, fh, acc0, 0, 0, 0);
            acc1 = __builtin_amdgcn_mfma_f32_16x16x32_bf16(a1, fh, acc1, 0, 0, 0);
        }

        // D layout (m89-verified): col = lane&15, row = (lane>>4)*4 + reg
        #pragma unroll
        for (int j = 0; j < 4; ++j) {
            const int r = kg * 4 + j;
            S[r][wid * 16 + col]      = valid ? acc0[j] * scale : NEG;
            S[r + 16][wid * 16 + col] = valid ? acc1[j] * scale : NEG;
        }
    }
    __syncthreads();

    // ---- P2: per-row partials: 8 threads/row x 8 cols each ----
    {
        const int r = tid >> 3;                 // row 0..31
        const int g = tid & 7;                  // 8-lane group position
        float m = NEG, s = 0.f;
        float v[8]; int ji[8];
        #pragma unroll
        for (int k = 0; k < 8; ++k) { v[k] = NEG; ji[k] = 0x7ffffffe; }

        #pragma unroll
        for (int e = 0; e < 8; ++e) {
            const int c  = g * 8 + e;
            const float x = S[r][c];
            const int  gi = blockIdx.x * 64 + c;
            if (x > -5e29f) {                   // skip invalid-key sentinels
                const float nm = fmaxf(m, x);
                s = s * __expf(m - nm) + __expf(x - nm);
                m = nm;
                top8_insert(v, ji, x, gi);
            }
        }

        // group (m,s) combine over 8 lanes
        #pragma unroll
        for (int off = 1; off < 8; off <<= 1) {
            float om = __shfl_xor(m, off), os = __shfl_xor(s, off);
            float M2 = fmaxf(m, om);
            s = s * __expf(m - M2) + os * __expf(om - M2);
            m = M2;
        }

        // group top-8 selection (8 rounds over 8 sorted lists)
        float sel_v[8]; int sel_i[8];
        #pragma unroll
        for (int rr = 0; rr < 8; ++rr) {
            float mv = v[0]; int mi = ji[0];
            #pragma unroll
            for (int off = 1; off < 8; off <<= 1) {
                float ov = __shfl_xor(mv, off);
                int   oi = __shfl_xor(mi, off);
                if (ov > mv || (ov == mv && oi < mi)) { mv = ov; mi = oi; }
            }
            if (v[0] == mv && ji[0] == mi) {    // I won: pop my head
                #pragma unroll
                for (int k = 0; k < 7; ++k) { v[k] = v[k + 1]; ji[k] = ji[k + 1]; }
                v[7] = NEG; ji[7] = 0x7ffffffe;
            }
            sel_v[rr] = mv; sel_i[rr] = mi;
        }

        if (g == 0) {
            const size_t base = (size_t)r * NTB + blockIdx.x;
            pmg[base] = m; psg[base] = s;
            #pragma unroll
            for (int k = 0; k < 8; ++k) {
                cvg[base * 8 + k] = sel_v[k];
                cig[base * 8 + k] = sel_i[k];
            }
        }
    }
}

// ---- K2: producers (32) merge+rescore -> tidx+flag; consumers (1024) gather
__global__ __launch_bounds__(256) void merge_gather_kernel(
    const float* __restrict__ pmg, const float* __restrict__ psg,
    const float* __restrict__ cvg, const int* __restrict__ cig,
    const float* __restrict__ q, const float* __restrict__ keys,
    const float* __restrict__ values,
    float* __restrict__ out_w, float* __restrict__ out_v,
    int* __restrict__ tidx, unsigned* __restrict__ flags,
    int NTB, int LDV)
{
    const int bid = blockIdx.x;
    const int tid = threadIdx.x;

    if (bid < 32) {
        // ================= producer: R8 row_merge verbatim =================
        const int b    = bid;
        const int lane = tid & 63;
        const int wid  = tid >> 6;
        const float scale = 0.04419417382415922f;

        __shared__ float lm[4], ls[4], lcv[4][TOPK];
        __shared__ int   lci[4][TOPK];

        float m = NEG, s = 0.f;
        float v[8]; int ji[8];
        #pragma unroll
        for (int k = 0; k < 8; ++k) { v[k] = NEG; ji[k] = 0x7ffffffe; }

        for (int tb = tid; tb < NTB; tb += 256) {
            const size_t base = (size_t)b * NTB + tb;
            const float pm_t = pmg[base], ps_t = psg[base];
            const float M2 = fmaxf(m, pm_t);
            s = s * __expf(m - M2) + ps_t * __expf(pm_t - M2);
            m = M2;
            #pragma unroll
            for (int k = 0; k < 8; ++k) {
                top8_insert(v, ji, cvg[base * 8 + k], cig[base * 8 + k]);
            }
        }

        #pragma unroll
        for (int off = 1; off < 64; off <<= 1) {
            float om = __shfl_xor(m, off), os = __shfl_xor(s, off);
            float M2 = fmaxf(m, om);
            s = s * __expf(m - M2) + os * __expf(om - M2);
            m = M2;
        }

        float selv = 0.f; int seli = 0;
        #pragma unroll
        for (int r = 0; r < TOPK; ++r) {
            float mv = v[0]; int mi = ji[0];
            wave_argmax(mv, mi);
            if (v[0] == mv && ji[0] == mi) {
                #pragma unroll
                for (int k = 0; k < TOPK - 1; ++k) { v[k] = v[k + 1]; ji[k] = ji[k + 1]; }
                v[TOPK - 1] = NEG; ji[TOPK - 1] = 0x7ffffffe;
            }
            if (lane == r) { selv = mv; seli = mi; }
        }

        if (lane == 0) { lm[wid] = m; ls[wid] = s; }
        if (lane < TOPK) { lcv[wid][lane] = selv; lci[wid][lane] = seli; }
        __syncthreads();

        if (wid != 0) return;

        float M = lm[0], S = ls[0];
        #pragma unroll
        for (int cc = 1; cc < 4; ++cc) {
            float M2 = fmaxf(M, lm[cc]);
            S = S * __expf(M - M2) + ls[cc] * __expf(lm[cc] - M2);
            M = M2;
        }

        float vv = (lane < 32) ? lcv[lane >> 3][lane & 7] : NEG;
        int   ii = (lane < 32) ? lci[lane >> 3][lane & 7] : 0x7ffffffe;
        int   si = 0x7ffffffe;
        #pragma unroll
        for (int r = 0; r < 12; ++r) {
            float mv = vv; int mi = ii;
            wave_argmax(mv, mi);
            if (vv == mv && ii == mi) vv = NEG;
            if (lane == r) si = mi;
        }

        float4 qa = *reinterpret_cast<const float4*>(q + (size_t)b * DKD + lane * 8);
        float4 qb = *reinterpret_cast<const float4*>(q + (size_t)b * DKD + lane * 8 + 4);
        float exv = NEG;
        #pragma unroll
        for (int r = 0; r < 12; ++r) {
            const int cand = __shfl(si, r);
            const float* kr = keys + (size_t)cand * DKD + lane * 8;
            float4 k1 = *reinterpret_cast<const float4*>(kr);
            float4 k2 = *reinterpret_cast<const float4*>(kr + 4);
            float p = qa.x * k1.x + qa.y * k1.y + qa.z * k1.z + qa.w * k1.w
                    + qb.x * k2.x + qb.y * k2.y + qb.z * k2.z + qb.w * k2.w;
            #pragma unroll
            for (int off = 1; off < 64; off <<= 1) p += __shfl_xor(p, off);
            if (lane == r) exv = p * scale;
        }

        float fv = (lane < 12) ? exv : NEG;
        int   fi = (lane < 12) ? si : 0x7ffffffe;
        #pragma unroll
        for (int r = 0; r < TOPK; ++r) {
            float mv = fv; int mi = fi;
            wave_argmax(mv, mi);
            if (fv == mv && fi == mi) fv = NEG;
            if (lane == r) {
                out_w[b * TOPK + r] = __expf(mv - M) / S;
                tidx[b * TOPK + r]  = mi;
            }
        }
        // publish: release makes the wave's tidx stores visible agent-wide
        if (lane == 0)
            __hip_atomic_store(&flags[b], 1u, __ATOMIC_RELEASE,
                               __HIP_MEMORY_SCOPE_AGENT);
    } else {
        // ================= consumer: wait for own row, then gather =========
        const int cid = bid - 32;
        const int bk  = cid >> 2;               // output row 0..255
        const int qtr = cid & 3;
        const int row = bk >> 3;                // query row 0..31

        __shared__ int s_id;
        if (tid == 0) {
            while (__hip_atomic_load(&flags[row], __ATOMIC_ACQUIRE,
                                     __HIP_MEMORY_SCOPE_AGENT) == 0u) {
                __builtin_amdgcn_s_sleep(2);
            }
            s_id = tidx[bk];                    // after acquire: fresh
        }
        __syncthreads();

        const int id = s_id;
        const float4* src = reinterpret_cast<const float4*>(values + (size_t)id * LDV);
        float4*       dst = reinterpret_cast<float4*>(out_v + (size_t)bk * LDV);
        const int n4 = LDV >> 2;                // 2560
        const int qn = n4 >> 2;                 // 640
        for (int i = qtr * qn + tid; i < (qtr + 1) * qn; i += 256)
            dst[i] = src[i];
    }
}

extern "C" void kernel_launch(void* const* d_in, const int* in_sizes, int n_in,
                              void* d_out, int out_size, void* d_ws, size_t ws_size,
                              hipStream_t stream) {
    const float* q      = (const float*)d_in[0];
    const float* keys   = (const float*)d_in[1];
    const float* values = (const float*)d_in[2];

    const int B   = in_sizes[0] / DKD;                 // 32
    const int N   = in_sizes[1] / DKD;                 // 20000
    const int LDV = (int)((long long)in_sizes[2] / N); // 10240
    const int NTB = (N + 63) / 64;                     // 313

    float* out   = (float*)d_out;
    float* out_w = out;
    float* out_v = out + (size_t)B * TOPK;

    char* wsb = (char*)d_ws;
    size_t off = 0;
    float* pmg = (float*)(wsb + off); off += (size_t)B * NTB * sizeof(float);
    float* psg = (float*)(wsb + off); off += (size_t)B * NTB * sizeof(float);
    float* cvg = (float*)(wsb + off); off += (size_t)B * NTB * 8 * sizeof(float);
    int*   cig = (int*)(wsb + off);   off += (size_t)B * NTB * 8 * sizeof(int);
    int*   tidx = (int*)(wsb + off);  off += (size_t)B * TOPK * sizeof(int);
    unsigned* flags = (unsigned*)(wsb + off); off += B * sizeof(unsigned);

    // zero the per-row flags every launch (captured as a memset node)
    (void)hipMemsetAsync(flags, 0, B * sizeof(unsigned), stream);

    score_part_kernel<<<NTB, 256, 0, stream>>>(q, keys, pmg, psg, cvg, cig, N, NTB);
    merge_gather_kernel<<<32 + B * TOPK * 4, 256, 0, stream>>>(
        pmg, psg, cvg, cig, q, keys, values, out_w, out_v, tidx, flags, NTB, LDV);
}

// Round 12
// 135.665 us; speedup vs baseline: 2.4762x; 2.4762x over previous
//
#include <hip/hip_runtime.h>
#include <math.h>

// ---------------------------------------------------------------------------
// B=32 queries [B,512] fp32 vs N=20000 keys [N,512] fp32.
// scores = Q K^T / sqrt(512); softmax over N; top-8; gather values rows.
// Output = [B*8 weights f32] ++ [B*8 * 10240 values f32].
//
// R12: 2 kernels + 4B memset. NO spin anywhere (R4/R7/R11: all spin-sync
// forms are catastrophic). K2 is deleted via two moves:
//  K1 score_part+tail: R8-proven MFMA partials; then each block does
//     syncthreads + agent-scope ACQ_REL fetch_add on a counter; the LAST
//     block (all partials visible by acquire) merges 32 rows x 313 partials
//     -> per-row {M, S, top-12 idx} (~2KB). CUB-style last-block pattern,
//     no waiting.
//  K3 rescore_gather: 1024 blocks; wave 0 re-scores the 12 candidates
//     EXACTLY in fp32 (bitwise-identical across blocks -> consistent
//     selection), picks own rank's index, block gathers its quarter.
//     (krk==0,qtr==0) block writes the 8 weights.
// ---------------------------------------------------------------------------

#define TOPK 8
#define DKD 512
#define NEG  -1.0e30f

typedef __attribute__((ext_vector_type(8))) short short8;
typedef __attribute__((ext_vector_type(4))) float f32x4;

__device__ inline unsigned short f2bf(float x) {
    unsigned int u = __float_as_uint(x);
    u = (u + 0x7fffu + ((u >> 16) & 1u)) >> 16;   // RNE to bf16
    return (unsigned short)u;
}

// comparator everywhere: value desc, index asc (matches lax.top_k ties)
__device__ inline void wave_argmax(float& v, int& i) {
    #pragma unroll
    for (int off = 1; off < 64; off <<= 1) {
        float ov = __shfl_xor(v, off);
        int   oi = __shfl_xor(i, off);
        if (ov > v || (ov == v && oi < i)) { v = ov; i = oi; }
    }
}

// sorted-desc top-8 insert (strict > keeps earlier index on ties)
__device__ inline void top8_insert(float (&v)[8], int (&ji)[8], float x, int gi) {
    if (x > v[7]) {
        bool g[8];
        #pragma unroll
        for (int k = 0; k < 8; ++k) g[k] = (x > v[k]);
        #pragma unroll
        for (int k = 7; k >= 1; --k) {
            v[k]  = g[k] ? (g[k - 1] ? v[k - 1] : x)  : v[k];
            ji[k] = g[k] ? (g[k - 1] ? ji[k - 1] : gi) : ji[k];
        }
        v[0]  = g[0] ? x  : v[0];
        ji[0] = g[0] ? gi : ji[0];
    }
}

// sorted-desc top-12 insert
__device__ inline void top12_insert(float (&v)[12], int (&ji)[12], float x, int gi) {
    if (x > v[11]) {
        bool g[12];
        #pragma unroll
        for (int k = 0; k < 12; ++k) g[k] = (x > v[k]);
        #pragma unroll
        for (int k = 11; k >= 1; --k) {
            v[k]  = g[k] ? (g[k - 1] ? v[k - 1] : x)  : v[k];
            ji[k] = g[k] ? (g[k - 1] ? ji[k - 1] : gi) : ji[k];
        }
        v[0]  = g[0] ? x  : v[0];
        ji[0] = g[0] ? gi : ji[0];
    }
}

// ---- K1: MFMA scores (64 keys/block) + partials + last-block merge --------
__global__ __launch_bounds__(256) void score_part_kernel(
    const float* __restrict__ q, const float* __restrict__ keys,
    float* __restrict__ pmg, float* __restrict__ psg,
    float* __restrict__ cvg, int* __restrict__ cig,
    float* __restrict__ candM, float* __restrict__ candS,
    int* __restrict__ candI, unsigned* __restrict__ donecnt,
    int N, int NTB)
{
    const int tid  = threadIdx.x;
    const int lane = tid & 63;
    const int wid  = tid >> 6;
    const float scale = 0.04419417382415922f;   // 1/sqrt(512)

    __shared__ short qs[32][DKD + 8];   // bf16 q, +8 pad
    __shared__ float S[32][65];         // scores tile, +1 pad
    __shared__ unsigned s_last;

    // ---- P0: q -> bf16 into LDS ----
    #pragma unroll
    for (int i = 0; i < 16; ++i) {
        const int idx = i * 256 + tid;
        const int row = idx >> 7;
        const int c4  = idx & 127;
        float4 v = *reinterpret_cast<const float4*>(&q[row * DKD + c4 * 4]);
        ushort4 h;
        h.x = f2bf(v.x); h.y = f2bf(v.y); h.z = f2bf(v.z); h.w = f2bf(v.w);
        *reinterpret_cast<ushort4*>(&qs[row][c4 * 4]) = h;
    }
    __syncthreads();

    // ---- P1: 16-key MFMA tile per wave (R8-proven) ----
    {
        const int col = lane & 15;
        const int kg  = lane >> 4;
        const int n0  = blockIdx.x * 64 + wid * 16;

        f32x4 acc0 = {0.f, 0.f, 0.f, 0.f};
        f32x4 acc1 = {0.f, 0.f, 0.f, 0.f};

        int nrow = n0 + col;
        const bool valid = (nrow < N);
        if (!valid) nrow = N - 1;
        const float* krow = keys + (size_t)nrow * DKD + kg * 8;
        const short* s0 = &qs[col][kg * 8];
        const short* s1 = &qs[col + 16][kg * 8];

        #pragma unroll 4
        for (int ks = 0; ks < 16; ++ks) {
            const int d = ks * 32;
            float4 ka = *reinterpret_cast<const float4*>(krow + d);
            float4 kb = *reinterpret_cast<const float4*>(krow + d + 4);
            short8 fh;
            fh[0] = (short)f2bf(ka.x); fh[1] = (short)f2bf(ka.y);
            fh[2] = (short)f2bf(ka.z); fh[3] = (short)f2bf(ka.w);
            fh[4] = (short)f2bf(kb.x); fh[5] = (short)f2bf(kb.y);
            fh[6] = (short)f2bf(kb.z); fh[7] = (short)f2bf(kb.w);
            short8 a0 = *reinterpret_cast<const short8*>(s0 + d);
            short8 a1 = *reinterpret_cast<const short8*>(s1 + d);
            acc0 = __builtin_amdgcn_mfma_f32_16x16x32_bf16(a0, fh, acc0, 0, 0, 0);
            acc1 = __builtin_amdgcn_mfma_f32_16x16x32_bf16(a1, fh, acc1, 0, 0, 0);
        }

        #pragma unroll
        for (int j = 0; j < 4; ++j) {
            const int r = kg * 4 + j;
            S[r][wid * 16 + col]      = valid ? acc0[j] * scale : NEG;
            S[r + 16][wid * 16 + col] = valid ? acc1[j] * scale : NEG;
        }
    }
    __syncthreads();

    // ---- P2: per-row partials: 8 threads/row x 8 cols each (R8-proven) ----
    {
        const int r = tid >> 3;
        const int g = tid & 7;
        float m = NEG, s = 0.f;
        float v[8]; int ji[8];
        #pragma unroll
        for (int k = 0; k < 8; ++k) { v[k] = NEG; ji[k] = 0x7ffffffe; }

        #pragma unroll
        for (int e = 0; e < 8; ++e) {
            const int c  = g * 8 + e;
            const float x = S[r][c];
            const int  gi = blockIdx.x * 64 + c;
            if (x > -5e29f) {
                const float nm = fmaxf(m, x);
                s = s * __expf(m - nm) + __expf(x - nm);
                m = nm;
                top8_insert(v, ji, x, gi);
            }
        }

        #pragma unroll
        for (int off = 1; off < 8; off <<= 1) {
            float om = __shfl_xor(m, off), os = __shfl_xor(s, off);
            float M2 = fmaxf(m, om);
            s = s * __expf(m - M2) + os * __expf(om - M2);
            m = M2;
        }

        float sel_v[8]; int sel_i[8];
        #pragma unroll
        for (int rr = 0; rr < 8; ++rr) {
            float mv = v[0]; int mi = ji[0];
            #pragma unroll
            for (int off = 1; off < 8; off <<= 1) {
                float ov = __shfl_xor(mv, off);
                int   oi = __shfl_xor(mi, off);
                if (ov > mv || (ov == mv && oi < mi)) { mv = ov; mi = oi; }
            }
            if (v[0] == mv && ji[0] == mi) {
                #pragma unroll
                for (int k = 0; k < 7; ++k) { v[k] = v[k + 1]; ji[k] = ji[k + 1]; }
                v[7] = NEG; ji[7] = 0x7ffffffe;
            }
            sel_v[rr] = mv; sel_i[rr] = mi;
        }

        if (g == 0) {
            const size_t base = (size_t)r * NTB + blockIdx.x;
            pmg[base] = m; psg[base] = s;
            #pragma unroll
            for (int k = 0; k < 8; ++k) {
                cvg[base * 8 + k] = sel_v[k];
                cig[base * 8 + k] = sel_i[k];
            }
        }
    }

    // ---- P3: last-block detection (no waiting) ----
    __syncthreads();   // drains vmcnt: all this block's partial stores in L2
    if (tid == 0) {
        // ACQ_REL agent scope: release flushes this XCD's L2; the block that
        // sees old==NTB-1 has acquire -> all other blocks' partials visible.
        unsigned old = __hip_atomic_fetch_add(donecnt, 1u, __ATOMIC_ACQ_REL,
                                              __HIP_MEMORY_SCOPE_AGENT);
        s_last = (old == (unsigned)(NTB - 1)) ? 1u : 0u;
    }
    __syncthreads();
    if (!s_last) return;

    // ---- P4: merge tail (ONE block): 32 rows, 8 threads/row ----
    {
        const int r = tid >> 3;                 // row 0..31
        const int g = tid & 7;
        float m = NEG, s = 0.f;
        float v[12]; int ji[12];
        #pragma unroll
        for (int k = 0; k < 12; ++k) { v[k] = NEG; ji[k] = 0x7ffffffe; }

        for (int tb = g; tb < NTB; tb += 8) {
            const size_t base = (size_t)r * NTB + tb;
            const float pm_t = pmg[base], ps_t = psg[base];
            const float M2 = fmaxf(m, pm_t);
            s = s * __expf(m - M2) + ps_t * __expf(pm_t - M2);
            m = M2;
            #pragma unroll
            for (int k = 0; k < 8; ++k)
                top12_insert(v, ji, cvg[base * 8 + k], cig[base * 8 + k]);
        }

        // 8-lane (m,s) combine (lane groups aligned: lane = (r&7)*8+g)
        #pragma unroll
        for (int off = 1; off < 8; off <<= 1) {
            float om = __shfl_xor(m, off), os = __shfl_xor(s, off);
            float M2 = fmaxf(m, om);
            s = s * __expf(m - M2) + os * __expf(om - M2);
            m = M2;
        }

        // 12 selection rounds over 8x12 sorted lists -> exact top-12
        int out_i[12];
        #pragma unroll
        for (int rr = 0; rr < 12; ++rr) {
            float mv = v[0]; int mi = ji[0];
            #pragma unroll
            for (int off = 1; off < 8; off <<= 1) {
                float ov = __shfl_xor(mv, off);
                int   oi = __shfl_xor(mi, off);
                if (ov > mv || (ov == mv && oi < mi)) { mv = ov; mi = oi; }
            }
            if (v[0] == mv && ji[0] == mi) {
                #pragma unroll
                for (int k = 0; k < 11; ++k) { v[k] = v[k + 1]; ji[k] = ji[k + 1]; }
                v[11] = NEG; ji[11] = 0x7ffffffe;
            }
            out_i[rr] = mi;
        }

        if (g == 0) {
            candM[r] = m; candS[r] = s;
            #pragma unroll
            for (int k = 0; k < 12; ++k) candI[r * 12 + k] = out_i[k];
        }
    }
}

// ---- K3: per (out-row, quarter): exact rescore of 12 -> own idx -> gather -
__global__ __launch_bounds__(256) void rescore_gather_kernel(
    const float* __restrict__ candM, const float* __restrict__ candS,
    const int* __restrict__ candI,
    const float* __restrict__ q, const float* __restrict__ keys,
    const float* __restrict__ values,
    float* __restrict__ out_w, float* __restrict__ out_v, int LDV)
{
    const int bk   = blockIdx.x >> 2;           // output row 0..255
    const int qtr  = blockIdx.x & 3;
    const int b    = bk >> 3;                   // query row
    const int krk  = bk & 7;                    // rank within top-8
    const int tid  = threadIdx.x;
    const int lane = tid & 63;
    const int wid  = tid >> 6;
    const float scale = 0.04419417382415922f;

    __shared__ int s_id;

    if (wid == 0) {
        const float M = candM[b];
        const float S = candS[b];
        int si = (lane < 12) ? candI[b * 12 + lane] : 0x7ffffffe;

        // exact fp32 rescore of the 12 candidates (R8-proven, bitwise
        // identical across all blocks of this row -> consistent selection)
        float4 qa = *reinterpret_cast<const float4*>(q + (size_t)b * DKD + lane * 8);
        float4 qb = *reinterpret_cast<const float4*>(q + (size_t)b * DKD + lane * 8 + 4);
        float exv = NEG;
        #pragma unroll
        for (int r = 0; r < 12; ++r) {
            const int cand = __shfl(si, r);
            const float* kr = keys + (size_t)cand * DKD + lane * 8;
            float4 k1 = *reinterpret_cast<const float4*>(kr);
            float4 k2 = *reinterpret_cast<const float4*>(kr + 4);
            float p = qa.x * k1.x + qa.y * k1.y + qa.z * k1.z + qa.w * k1.w
                    + qb.x * k2.x + qb.y * k2.y + qb.z * k2.z + qb.w * k2.w;
            #pragma unroll
            for (int off = 1; off < 64; off <<= 1) p += __shfl_xor(p, off);
            if (lane == r) exv = p * scale;
        }

        // exact top-8 of 12; stash own rank's index; writer block -> weights
        float fv = (lane < 12) ? exv : NEG;
        int   fi = (lane < 12) ? si : 0x7ffffffe;
        #pragma unroll
        for (int r = 0; r < TOPK; ++r) {
            float mv = fv; int mi = fi;
            wave_argmax(mv, mi);
            if (fv == mv && fi == mi) fv = NEG;
            if (lane == r) {
                if (r == krk) s_id = mi;
                if (qtr == 0 && krk == 0)
                    out_w[b * TOPK + r] = __expf(mv - M) / S;
            }
        }
    }
    __syncthreads();

    // gather this (row, quarter) segment
    const int id = s_id;
    const float4* src = reinterpret_cast<const float4*>(values + (size_t)id * LDV);
    float4*       dst = reinterpret_cast<float4*>(out_v + (size_t)bk * LDV);
    const int n4 = LDV >> 2;                    // 2560
    const int qn = n4 >> 2;                     // 640
    for (int i = qtr * qn + tid; i < (qtr + 1) * qn; i += 256)
        dst[i] = src[i];
}

extern "C" void kernel_launch(void* const* d_in, const int* in_sizes, int n_in,
                              void* d_out, int out_size, void* d_ws, size_t ws_size,
                              hipStream_t stream) {
    const float* q      = (const float*)d_in[0];
    const float* keys   = (const float*)d_in[1];
    const float* values = (const float*)d_in[2];

    const int B   = in_sizes[0] / DKD;                 // 32
    const int N   = in_sizes[1] / DKD;                 // 20000
    const int LDV = (int)((long long)in_sizes[2] / N); // 10240
    const int NTB = (N + 63) / 64;                     // 313

    float* out   = (float*)d_out;
    float* out_w = out;
    float* out_v = out + (size_t)B * TOPK;

    char* wsb = (char*)d_ws;
    size_t off = 0;
    float* pmg = (float*)(wsb + off); off += (size_t)B * NTB * sizeof(float);
    float* psg = (float*)(wsb + off); off += (size_t)B * NTB * sizeof(float);
    float* cvg = (float*)(wsb + off); off += (size_t)B * NTB * 8 * sizeof(float);
    int*   cig = (int*)(wsb + off);   off += (size_t)B * NTB * 8 * sizeof(int);
    float* candM = (float*)(wsb + off); off += B * sizeof(float);
    float* candS = (float*)(wsb + off); off += B * sizeof(float);
    int*   candI = (int*)(wsb + off);   off += (size_t)B * 12 * sizeof(int);
    unsigned* donecnt = (unsigned*)(wsb + off); off += sizeof(unsigned);

    // counter must be 0 at every launch (captured as a tiny memset node)
    (void)hipMemsetAsync(donecnt, 0, sizeof(unsigned), stream);

    score_part_kernel<<<NTB, 256, 0, stream>>>(
        q, keys, pmg, psg, cvg, cig, candM, candS, candI, donecnt, N, NTB);
    rescore_gather_kernel<<<B * TOPK * 4, 256, 0, stream>>>(
        candM, candS, candI, q, keys, values, out_w, out_v, LDV);
}

// Round 13
// 47.062 us; speedup vs baseline: 7.1382x; 2.8827x over previous
//
#include <hip/hip_runtime.h>
#include <math.h>

// ---------------------------------------------------------------------------
// B=32 queries [B,512] fp32 vs N=20000 keys [N,512] fp32.
// scores = Q K^T / sqrt(512); softmax over N; top-8; gather values rows.
// Output = [B*8 weights f32] ++ [B*8 * 10240 values f32].
//
// R13: exactly 2 graph nodes, no atomics, no memset (R12 proved even one
// agent-scope atomic per block costs ~90us; only plain kernel edges work).
//  K1 score_part: R8-proven VERBATIM (64 keys/block, MFMA, in-block
//     per-row (m, sum-exp, top-8) partials).
//  K2 merge_gather: 256 blocks = one per OUTPUT row (b=bk>>3, krk=bk&7).
//     Each block redundantly runs the R8 merge for its query row (x8
//     redundancy, L2-hot 22.5KB, bitwise-identical fp -> consistent
//     selection), wave 0 exact-rescores top-12 (fp32), stashes own rank's
//     index in LDS; all 4 waves gather the full 40KB row with 10 loads
//     in flight before stores (keeps gather BW-bound at 256 blocks).
//     krk==0 blocks write the 8 weights.
// ---------------------------------------------------------------------------

#define TOPK 8
#define DKD 512
#define NEG  -1.0e30f

typedef __attribute__((ext_vector_type(8))) short short8;
typedef __attribute__((ext_vector_type(4))) float f32x4;

__device__ inline unsigned short f2bf(float x) {
    unsigned int u = __float_as_uint(x);
    u = (u + 0x7fffu + ((u >> 16) & 1u)) >> 16;   // RNE to bf16
    return (unsigned short)u;
}

// comparator everywhere: value desc, index asc (matches lax.top_k ties)
__device__ inline void wave_argmax(float& v, int& i) {
    #pragma unroll
    for (int off = 1; off < 64; off <<= 1) {
        float ov = __shfl_xor(v, off);
        int   oi = __shfl_xor(i, off);
        if (ov > v || (ov == v && oi < i)) { v = ov; i = oi; }
    }
}

// sorted-desc top-8 insert (strict > keeps earlier index on ties)
__device__ inline void top8_insert(float (&v)[8], int (&ji)[8], float x, int gi) {
    if (x > v[7]) {
        bool g[8];
        #pragma unroll
        for (int k = 0; k < 8; ++k) g[k] = (x > v[k]);
        #pragma unroll
        for (int k = 7; k >= 1; --k) {
            v[k]  = g[k] ? (g[k - 1] ? v[k - 1] : x)  : v[k];
            ji[k] = g[k] ? (g[k - 1] ? ji[k - 1] : gi) : ji[k];
        }
        v[0]  = g[0] ? x  : v[0];
        ji[0] = g[0] ? gi : ji[0];
    }
}

// ---- K1: MFMA scores (64 keys/block) + in-block per-row partials ----------
// R8-proven VERBATIM.
__global__ __launch_bounds__(256) void score_part_kernel(
    const float* __restrict__ q, const float* __restrict__ keys,
    float* __restrict__ pmg, float* __restrict__ psg,
    float* __restrict__ cvg, int* __restrict__ cig, int N, int NTB)
{
    const int tid  = threadIdx.x;
    const int lane = tid & 63;
    const int wid  = tid >> 6;
    const float scale = 0.04419417382415922f;   // 1/sqrt(512)

    __shared__ short qs[32][DKD + 8];   // bf16 q, +8 pad (2-way banks = free)
    __shared__ float S[32][65];         // scores tile, +1 pad

    // ---- P0: q -> bf16 into LDS (64KB read, 1x per block) ----
    #pragma unroll
    for (int i = 0; i < 16; ++i) {
        const int idx = i * 256 + tid;          // 0..4095 float4s
        const int row = idx >> 7;               // 128 float4 per row
        const int c4  = idx & 127;
        float4 v = *reinterpret_cast<const float4*>(&q[row * DKD + c4 * 4]);
        ushort4 h;
        h.x = f2bf(v.x); h.y = f2bf(v.y); h.z = f2bf(v.z); h.w = f2bf(v.w);
        *reinterpret_cast<ushort4*>(&qs[row][c4 * 4]) = h;
    }
    __syncthreads();

    // ---- P1: 16-key MFMA tile per wave ----
    {
        const int col = lane & 15;
        const int kg  = lane >> 4;
        const int n0  = blockIdx.x * 64 + wid * 16;

        f32x4 acc0 = {0.f, 0.f, 0.f, 0.f};
        f32x4 acc1 = {0.f, 0.f, 0.f, 0.f};

        int nrow = n0 + col;
        const bool valid = (nrow < N);
        if (!valid) nrow = N - 1;               // clamp loads
        const float* krow = keys + (size_t)nrow * DKD + kg * 8;
        const short* s0 = &qs[col][kg * 8];
        const short* s1 = &qs[col + 16][kg * 8];

        #pragma unroll 4
        for (int ks = 0; ks < 16; ++ks) {
            const int d = ks * 32;
            float4 ka = *reinterpret_cast<const float4*>(krow + d);
            float4 kb = *reinterpret_cast<const float4*>(krow + d + 4);
            short8 fh;
            fh[0] = (short)f2bf(ka.x); fh[1] = (short)f2bf(ka.y);
            fh[2] = (short)f2bf(ka.z); fh[3] = (short)f2bf(ka.w);
            fh[4] = (short)f2bf(kb.x); fh[5] = (short)f2bf(kb.y);
            fh[6] = (short)f2bf(kb.z); fh[7] = (short)f2bf(kb.w);
            short8 a0 = *reinterpret_cast<const short8*>(s0 + d);
            short8 a1 = *reinterpret_cast<const short8*>(s1 + d);
            acc0 = __builtin_amdgcn_mfma_f32_16x16x32_bf16(a0, fh, acc0, 0, 0, 0);
            acc1 = __builtin_amdgcn_mfma_f32_16x16x32_bf16(a1, fh, acc1, 0, 0, 0);
        }

        // D layout (m89-verified): col = lane&15, row = (lane>>4)*4 + reg
        #pragma unroll
        for (int j = 0; j < 4; ++j) {
            const int r = kg * 4 + j;
            S[r][wid * 16 + col]      = valid ? acc0[j] * scale : NEG;
            S[r + 16][wid * 16 + col] = valid ? acc1[j] * scale : NEG;
        }
    }
    __syncthreads();

    // ---- P2: per-row partials: 8 threads/row x 8 cols each ----
    {
        const int r = tid >> 3;                 // row 0..31
        const int g = tid & 7;                  // 8-lane group position
        float m = NEG, s = 0.f;
        float v[8]; int ji[8];
        #pragma unroll
        for (int k = 0; k < 8; ++k) { v[k] = NEG; ji[k] = 0x7ffffffe; }

        #pragma unroll
        for (int e = 0; e < 8; ++e) {
            const int c  = g * 8 + e;
            const float x = S[r][c];
            const int  gi = blockIdx.x * 64 + c;
            if (x > -5e29f) {                   // skip invalid-key sentinels
                const float nm = fmaxf(m, x);
                s = s * __expf(m - nm) + __expf(x - nm);
                m = nm;
                top8_insert(v, ji, x, gi);
            }
        }

        // group (m,s) combine over 8 lanes
        #pragma unroll
        for (int off = 1; off < 8; off <<= 1) {
            float om = __shfl_xor(m, off), os = __shfl_xor(s, off);
            float M2 = fmaxf(m, om);
            s = s * __expf(m - M2) + os * __expf(om - M2);
            m = M2;
        }

        // group top-8 selection (8 rounds over 8 sorted lists)
        float sel_v[8]; int sel_i[8];
        #pragma unroll
        for (int rr = 0; rr < 8; ++rr) {
            float mv = v[0]; int mi = ji[0];
            #pragma unroll
            for (int off = 1; off < 8; off <<= 1) {
                float ov = __shfl_xor(mv, off);
                int   oi = __shfl_xor(mi, off);
                if (ov > mv || (ov == mv && oi < mi)) { mv = ov; mi = oi; }
            }
            if (v[0] == mv && ji[0] == mi) {    // I won: pop my head
                #pragma unroll
                for (int k = 0; k < 7; ++k) { v[k] = v[k + 1]; ji[k] = ji[k + 1]; }
                v[7] = NEG; ji[7] = 0x7ffffffe;
            }
            sel_v[rr] = mv; sel_i[rr] = mi;
        }

        if (g == 0) {
            const size_t base = (size_t)r * NTB + blockIdx.x;
            pmg[base] = m; psg[base] = s;
            #pragma unroll
            for (int k = 0; k < 8; ++k) {
                cvg[base * 8 + k] = sel_v[k];
                cig[base * 8 + k] = sel_i[k];
            }
        }
    }
}

// ---- K2: 256 blocks = one per output row: merge -> rescore -> gather ------
__global__ __launch_bounds__(256) void merge_gather_kernel(
    const float* __restrict__ pmg, const float* __restrict__ psg,
    const float* __restrict__ cvg, const int* __restrict__ cig,
    const float* __restrict__ q, const float* __restrict__ keys,
    const float* __restrict__ values,
    float* __restrict__ out_w, float* __restrict__ out_v, int NTB, int LDV)
{
    const int bk   = blockIdx.x;                // output row 0..255
    const int b    = bk >> 3;                   // query row
    const int krk  = bk & 7;                    // rank within top-8
    const int tid  = threadIdx.x;
    const int lane = tid & 63;
    const int wid  = tid >> 6;
    const float scale = 0.04419417382415922f;

    __shared__ float lm[4], ls[4], lcv[4][TOPK];
    __shared__ int   lci[4][TOPK];
    __shared__ int   s_id;

    // ---- thread-local: combine ~2 tiles' partials (R8-proven merge) ----
    float m = NEG, s = 0.f;
    float v[8]; int ji[8];
    #pragma unroll
    for (int k = 0; k < 8; ++k) { v[k] = NEG; ji[k] = 0x7ffffffe; }

    for (int tb = tid; tb < NTB; tb += 256) {
        const size_t base = (size_t)b * NTB + tb;
        const float pm_t = pmg[base], ps_t = psg[base];
        const float M2 = fmaxf(m, pm_t);
        s = s * __expf(m - M2) + ps_t * __expf(pm_t - M2);
        m = M2;
        #pragma unroll
        for (int k = 0; k < 8; ++k) {
            top8_insert(v, ji, cvg[base * 8 + k], cig[base * 8 + k]);
        }
    }

    // ---- wave-level (m,s) combine ----
    #pragma unroll
    for (int off = 1; off < 64; off <<= 1) {
        float om = __shfl_xor(m, off), os = __shfl_xor(s, off);
        float M2 = fmaxf(m, om);
        s = s * __expf(m - M2) + os * __expf(om - M2);
        m = M2;
    }

    // ---- wave-level top-8 merge: 8 selection rounds ----
    float selv = 0.f; int seli = 0;
    #pragma unroll
    for (int r = 0; r < TOPK; ++r) {
        float mv = v[0]; int mi = ji[0];
        wave_argmax(mv, mi);
        if (v[0] == mv && ji[0] == mi) {       // I won: pop my head
            #pragma unroll
            for (int k = 0; k < TOPK - 1; ++k) { v[k] = v[k + 1]; ji[k] = ji[k + 1]; }
            v[TOPK - 1] = NEG; ji[TOPK - 1] = 0x7ffffffe;
        }
        if (lane == r) { selv = mv; seli = mi; }
    }

    if (lane == 0) { lm[wid] = m; ls[wid] = s; }
    if (lane < TOPK) { lcv[wid][lane] = selv; lci[wid][lane] = seli; }
    __syncthreads();

    if (wid == 0) {
        // ---- cross-wave combine (all lanes of wave 0 redundantly) ----
        float M = lm[0], S = ls[0];
        #pragma unroll
        for (int cc = 1; cc < 4; ++cc) {
            float M2 = fmaxf(M, lm[cc]);
            S = S * __expf(M - M2) + ls[cc] * __expf(lm[cc] - M2);
            M = M2;
        }

        // ---- 32 candidates -> approx top-12 ----
        float vv = (lane < 32) ? lcv[lane >> 3][lane & 7] : NEG;
        int   ii = (lane < 32) ? lci[lane >> 3][lane & 7] : 0x7ffffffe;
        int   si = 0x7ffffffe;
        #pragma unroll
        for (int r = 0; r < 12; ++r) {
            float mv = vv; int mi = ii;
            wave_argmax(mv, mi);
            if (vv == mv && ii == mi) vv = NEG;
            if (lane == r) si = mi;
        }

        // ---- exact fp32 rescore of the 12 candidates (bitwise identical
        //      across this row's 8 blocks -> consistent selection) ----
        float4 qa = *reinterpret_cast<const float4*>(q + (size_t)b * DKD + lane * 8);
        float4 qb = *reinterpret_cast<const float4*>(q + (size_t)b * DKD + lane * 8 + 4);
        float exv = NEG;
        #pragma unroll
        for (int r = 0; r < 12; ++r) {
            const int cand = __shfl(si, r);
            const float* kr = keys + (size_t)cand * DKD + lane * 8;
            float4 k1 = *reinterpret_cast<const float4*>(kr);
            float4 k2 = *reinterpret_cast<const float4*>(kr + 4);
            float p = qa.x * k1.x + qa.y * k1.y + qa.z * k1.z + qa.w * k1.w
                    + qb.x * k2.x + qb.y * k2.y + qb.z * k2.z + qb.w * k2.w;
            #pragma unroll
            for (int off = 1; off < 64; off <<= 1) p += __shfl_xor(p, off);
            if (lane == r) exv = p * scale;
        }

        // ---- exact top-8 of 12; stash own rank's index; krk==0 -> weights --
        float fv = (lane < 12) ? exv : NEG;
        int   fi = (lane < 12) ? si : 0x7ffffffe;
        #pragma unroll
        for (int r = 0; r < TOPK; ++r) {
            float mv = fv; int mi = fi;
            wave_argmax(mv, mi);
            if (fv == mv && fi == mi) fv = NEG;
            if (lane == r) {
                if (r == krk) s_id = mi;
                if (krk == 0)
                    out_w[b * TOPK + r] = __expf(mv - M) / S;
            }
        }
    }
    __syncthreads();

    // ---- gather the full 40KB row; all 10 loads in flight before stores ----
    const int id = s_id;
    const float4* src = reinterpret_cast<const float4*>(values + (size_t)id * LDV);
    float4*       dst = reinterpret_cast<float4*>(out_v + (size_t)bk * LDV);
    // LDV/4 = 2560 = 10 * 256
    float4 buf[10];
    #pragma unroll
    for (int i = 0; i < 10; ++i) buf[i] = src[tid + i * 256];
    #pragma unroll
    for (int i = 0; i < 10; ++i) dst[tid + i * 256] = buf[i];
}

extern "C" void kernel_launch(void* const* d_in, const int* in_sizes, int n_in,
                              void* d_out, int out_size, void* d_ws, size_t ws_size,
                              hipStream_t stream) {
    const float* q      = (const float*)d_in[0];
    const float* keys   = (const float*)d_in[1];
    const float* values = (const float*)d_in[2];

    const int B   = in_sizes[0] / DKD;                 // 32
    const int N   = in_sizes[1] / DKD;                 // 20000
    const int LDV = (int)((long long)in_sizes[2] / N); // 10240
    const int NTB = (N + 63) / 64;                     // 313

    float* out   = (float*)d_out;
    float* out_w = out;
    float* out_v = out + (size_t)B * TOPK;

    char* wsb = (char*)d_ws;
    size_t off = 0;
    float* pmg = (float*)(wsb + off); off += (size_t)B * NTB * sizeof(float);
    float* psg = (float*)(wsb + off); off += (size_t)B * NTB * sizeof(float);
    float* cvg = (float*)(wsb + off); off += (size_t)B * NTB * 8 * sizeof(float);
    int*   cig = (int*)(wsb + off);   off += (size_t)B * NTB * 8 * sizeof(int);

    score_part_kernel<<<NTB, 256, 0, stream>>>(q, keys, pmg, psg, cvg, cig, N, NTB);
    merge_gather_kernel<<<B * TOPK, 256, 0, stream>>>(
        pmg, psg, cvg, cig, q, keys, values, out_w, out_v, NTB, LDV);
}

// Round 14
// 42.861 us; speedup vs baseline: 7.8378x; 1.0980x over previous
//
#include <hip/hip_runtime.h>
#include <math.h>

// ---------------------------------------------------------------------------
// B=32 queries [B,512] fp32 vs N=20000 keys [N,512] fp32.
// scores = Q K^T / sqrt(512); softmax over N; top-8; gather values rows.
// Output = [B*8 weights f32] ++ [B*8 * 10240 values f32].
//
// R14 = R13 with the K2 rescore parallelized (serial 12-round wave-0 chain
// was ~3us with waves 1-3 idle; now 4 waves x 3 candidates, LDS handoff,
// then every thread does a local exact 12-element sort -> uniform gather
// index with no extra sync).
//  K1 score_part: R8-proven VERBATIM.
//  K2 merge_gather: 256 blocks = one per output row. Merge (all waves) ->
//     cross-wave combine + top-12 selection (all waves, redundant) ->
//     wave w rescores candidates 3w..3w+2 exactly in fp32 -> LDS ->
//     per-thread exact sort of 12 -> krk==0 writes weights; all gather.
// ---------------------------------------------------------------------------

#define TOPK 8
#define DKD 512
#define NEG  -1.0e30f

typedef __attribute__((ext_vector_type(8))) short short8;
typedef __attribute__((ext_vector_type(4))) float f32x4;

__device__ inline unsigned short f2bf(float x) {
    unsigned int u = __float_as_uint(x);
    u = (u + 0x7fffu + ((u >> 16) & 1u)) >> 16;   // RNE to bf16
    return (unsigned short)u;
}

// comparator everywhere: value desc, index asc (matches lax.top_k ties)
__device__ inline void wave_argmax(float& v, int& i) {
    #pragma unroll
    for (int off = 1; off < 64; off <<= 1) {
        float ov = __shfl_xor(v, off);
        int   oi = __shfl_xor(i, off);
        if (ov > v || (ov == v && oi < i)) { v = ov; i = oi; }
    }
}

// sorted-desc top-8 insert (strict > keeps earlier index on ties)
__device__ inline void top8_insert(float (&v)[8], int (&ji)[8], float x, int gi) {
    if (x > v[7]) {
        bool g[8];
        #pragma unroll
        for (int k = 0; k < 8; ++k) g[k] = (x > v[k]);
        #pragma unroll
        for (int k = 7; k >= 1; --k) {
            v[k]  = g[k] ? (g[k - 1] ? v[k - 1] : x)  : v[k];
            ji[k] = g[k] ? (g[k - 1] ? ji[k - 1] : gi) : ji[k];
        }
        v[0]  = g[0] ? x  : v[0];
        ji[0] = g[0] ? gi : ji[0];
    }
}

// ---- K1: MFMA scores (64 keys/block) + in-block per-row partials ----------
// R8-proven VERBATIM.
__global__ __launch_bounds__(256) void score_part_kernel(
    const float* __restrict__ q, const float* __restrict__ keys,
    float* __restrict__ pmg, float* __restrict__ psg,
    float* __restrict__ cvg, int* __restrict__ cig, int N, int NTB)
{
    const int tid  = threadIdx.x;
    const int lane = tid & 63;
    const int wid  = tid >> 6;
    const float scale = 0.04419417382415922f;   // 1/sqrt(512)

    __shared__ short qs[32][DKD + 8];   // bf16 q, +8 pad (2-way banks = free)
    __shared__ float S[32][65];         // scores tile, +1 pad

    // ---- P0: q -> bf16 into LDS (64KB read, 1x per block) ----
    #pragma unroll
    for (int i = 0; i < 16; ++i) {
        const int idx = i * 256 + tid;          // 0..4095 float4s
        const int row = idx >> 7;               // 128 float4 per row
        const int c4  = idx & 127;
        float4 v = *reinterpret_cast<const float4*>(&q[row * DKD + c4 * 4]);
        ushort4 h;
        h.x = f2bf(v.x); h.y = f2bf(v.y); h.z = f2bf(v.z); h.w = f2bf(v.w);
        *reinterpret_cast<ushort4*>(&qs[row][c4 * 4]) = h;
    }
    __syncthreads();

    // ---- P1: 16-key MFMA tile per wave ----
    {
        const int col = lane & 15;
        const int kg  = lane >> 4;
        const int n0  = blockIdx.x * 64 + wid * 16;

        f32x4 acc0 = {0.f, 0.f, 0.f, 0.f};
        f32x4 acc1 = {0.f, 0.f, 0.f, 0.f};

        int nrow = n0 + col;
        const bool valid = (nrow < N);
        if (!valid) nrow = N - 1;               // clamp loads
        const float* krow = keys + (size_t)nrow * DKD + kg * 8;
        const short* s0 = &qs[col][kg * 8];
        const short* s1 = &qs[col + 16][kg * 8];

        #pragma unroll 4
        for (int ks = 0; ks < 16; ++ks) {
            const int d = ks * 32;
            float4 ka = *reinterpret_cast<const float4*>(krow + d);
            float4 kb = *reinterpret_cast<const float4*>(krow + d + 4);
            short8 fh;
            fh[0] = (short)f2bf(ka.x); fh[1] = (short)f2bf(ka.y);
            fh[2] = (short)f2bf(ka.z); fh[3] = (short)f2bf(ka.w);
            fh[4] = (short)f2bf(kb.x); fh[5] = (short)f2bf(kb.y);
            fh[6] = (short)f2bf(kb.z); fh[7] = (short)f2bf(kb.w);
            short8 a0 = *reinterpret_cast<const short8*>(s0 + d);
            short8 a1 = *reinterpret_cast<const short8*>(s1 + d);
            acc0 = __builtin_amdgcn_mfma_f32_16x16x32_bf16(a0, fh, acc0, 0, 0, 0);
            acc1 = __builtin_amdgcn_mfma_f32_16x16x32_bf16(a1, fh, acc1, 0, 0, 0);
        }

        // D layout (m89-verified): col = lane&15, row = (lane>>4)*4 + reg
        #pragma unroll
        for (int j = 0; j < 4; ++j) {
            const int r = kg * 4 + j;
            S[r][wid * 16 + col]      = valid ? acc0[j] * scale : NEG;
            S[r + 16][wid * 16 + col] = valid ? acc1[j] * scale : NEG;
        }
    }
    __syncthreads();

    // ---- P2: per-row partials: 8 threads/row x 8 cols each ----
    {
        const int r = tid >> 3;                 // row 0..31
        const int g = tid & 7;                  // 8-lane group position
        float m = NEG, s = 0.f;
        float v[8]; int ji[8];
        #pragma unroll
        for (int k = 0; k < 8; ++k) { v[k] = NEG; ji[k] = 0x7ffffffe; }

        #pragma unroll
        for (int e = 0; e < 8; ++e) {
            const int c  = g * 8 + e;
            const float x = S[r][c];
            const int  gi = blockIdx.x * 64 + c;
            if (x > -5e29f) {                   // skip invalid-key sentinels
                const float nm = fmaxf(m, x);
                s = s * __expf(m - nm) + __expf(x - nm);
                m = nm;
                top8_insert(v, ji, x, gi);
            }
        }

        // group (m,s) combine over 8 lanes
        #pragma unroll
        for (int off = 1; off < 8; off <<= 1) {
            float om = __shfl_xor(m, off), os = __shfl_xor(s, off);
            float M2 = fmaxf(m, om);
            s = s * __expf(m - M2) + os * __expf(om - M2);
            m = M2;
        }

        // group top-8 selection (8 rounds over 8 sorted lists)
        float sel_v[8]; int sel_i[8];
        #pragma unroll
        for (int rr = 0; rr < 8; ++rr) {
            float mv = v[0]; int mi = ji[0];
            #pragma unroll
            for (int off = 1; off < 8; off <<= 1) {
                float ov = __shfl_xor(mv, off);
                int   oi = __shfl_xor(mi, off);
                if (ov > mv || (ov == mv && oi < mi)) { mv = ov; mi = oi; }
            }
            if (v[0] == mv && ji[0] == mi) {    // I won: pop my head
                #pragma unroll
                for (int k = 0; k < 7; ++k) { v[k] = v[k + 1]; ji[k] = ji[k + 1]; }
                v[7] = NEG; ji[7] = 0x7ffffffe;
            }
            sel_v[rr] = mv; sel_i[rr] = mi;
        }

        if (g == 0) {
            const size_t base = (size_t)r * NTB + blockIdx.x;
            pmg[base] = m; psg[base] = s;
            #pragma unroll
            for (int k = 0; k < 8; ++k) {
                cvg[base * 8 + k] = sel_v[k];
                cig[base * 8 + k] = sel_i[k];
            }
        }
    }
}

// ---- K2: 256 blocks = one per output row: merge -> par. rescore -> gather -
__global__ __launch_bounds__(256) void merge_gather_kernel(
    const float* __restrict__ pmg, const float* __restrict__ psg,
    const float* __restrict__ cvg, const int* __restrict__ cig,
    const float* __restrict__ q, const float* __restrict__ keys,
    const float* __restrict__ values,
    float* __restrict__ out_w, float* __restrict__ out_v, int NTB, int LDV)
{
    const int bk   = blockIdx.x;                // output row 0..255
    const int b    = bk >> 3;                   // query row
    const int krk  = bk & 7;                    // rank within top-8
    const int tid  = threadIdx.x;
    const int lane = tid & 63;
    const int wid  = tid >> 6;
    const float scale = 0.04419417382415922f;

    __shared__ float lm[4], ls[4], lcv[4][TOPK];
    __shared__ int   lci[4][TOPK];
    __shared__ float s_exv[12];
    __shared__ int   s_sid[12];

    // ---- thread-local: combine ~2 tiles' partials (R8-proven merge) ----
    float m = NEG, s = 0.f;
    float v[8]; int ji[8];
    #pragma unroll
    for (int k = 0; k < 8; ++k) { v[k] = NEG; ji[k] = 0x7ffffffe; }

    for (int tb = tid; tb < NTB; tb += 256) {
        const size_t base = (size_t)b * NTB + tb;
        const float pm_t = pmg[base], ps_t = psg[base];
        const float M2 = fmaxf(m, pm_t);
        s = s * __expf(m - M2) + ps_t * __expf(pm_t - M2);
        m = M2;
        #pragma unroll
        for (int k = 0; k < 8; ++k) {
            top8_insert(v, ji, cvg[base * 8 + k], cig[base * 8 + k]);
        }
    }

    // ---- wave-level (m,s) combine ----
    #pragma unroll
    for (int off = 1; off < 64; off <<= 1) {
        float om = __shfl_xor(m, off), os = __shfl_xor(s, off);
        float M2 = fmaxf(m, om);
        s = s * __expf(m - M2) + os * __expf(om - M2);
        m = M2;
    }

    // ---- wave-level top-8 merge: 8 selection rounds ----
    float selv = 0.f; int seli = 0;
    #pragma unroll
    for (int r = 0; r < TOPK; ++r) {
        float mv = v[0]; int mi = ji[0];
        wave_argmax(mv, mi);
        if (v[0] == mv && ji[0] == mi) {       // I won: pop my head
            #pragma unroll
            for (int k = 0; k < TOPK - 1; ++k) { v[k] = v[k + 1]; ji[k] = ji[k + 1]; }
            v[TOPK - 1] = NEG; ji[TOPK - 1] = 0x7ffffffe;
        }
        if (lane == r) { selv = mv; seli = mi; }
    }

    if (lane == 0) { lm[wid] = m; ls[wid] = s; }
    if (lane < TOPK) { lcv[wid][lane] = selv; lci[wid][lane] = seli; }
    __syncthreads();

    // ---- cross-wave combine (ALL waves, redundant -> everyone has M,S) ----
    float M = lm[0], S = ls[0];
    #pragma unroll
    for (int cc = 1; cc < 4; ++cc) {
        float M2 = fmaxf(M, lm[cc]);
        S = S * __expf(M - M2) + ls[cc] * __expf(lm[cc] - M2);
        M = M2;
    }

    // ---- 32 candidates -> approx top-12 (ALL waves, identical result) ----
    {
        float vv = (lane < 32) ? lcv[lane >> 3][lane & 7] : NEG;
        int   ii = (lane < 32) ? lci[lane >> 3][lane & 7] : 0x7ffffffe;
        int   si = 0x7ffffffe;
        #pragma unroll
        for (int r = 0; r < 12; ++r) {
            float mv = vv; int mi = ii;
            wave_argmax(mv, mi);
            if (vv == mv && ii == mi) vv = NEG;
            if (lane == r) si = mi;
        }

        // ---- wave wid rescores candidates 3*wid .. 3*wid+2 (fp32 exact,
        //      identical FP order across the row's 8 blocks) ----
        float4 qa = *reinterpret_cast<const float4*>(q + (size_t)b * DKD + lane * 8);
        float4 qb = *reinterpret_cast<const float4*>(q + (size_t)b * DKD + lane * 8 + 4);
        #pragma unroll
        for (int t = 0; t < 3; ++t) {
            const int r = wid * 3 + t;
            const int cand = __shfl(si, r);
            const float* kr = keys + (size_t)cand * DKD + lane * 8;
            float4 k1 = *reinterpret_cast<const float4*>(kr);
            float4 k2 = *reinterpret_cast<const float4*>(kr + 4);
            float p = qa.x * k1.x + qa.y * k1.y + qa.z * k1.z + qa.w * k1.w
                    + qb.x * k2.x + qb.y * k2.y + qb.z * k2.z + qb.w * k2.w;
            #pragma unroll
            for (int off = 1; off < 64; off <<= 1) p += __shfl_xor(p, off);
            if (lane == 0) { s_exv[r] = p * scale; s_sid[r] = cand; }
        }
    }
    __syncthreads();

    // ---- per-thread exact sort of the 12 (value desc, index asc) ----
    // Deterministic and identical on every thread of every block of this row.
    float ev[12]; int eid[12];
    #pragma unroll
    for (int k = 0; k < 12; ++k) { ev[k] = s_exv[k]; eid[k] = s_sid[k]; }
    #pragma unroll
    for (int a = 1; a < 12; ++a) {
        float xv = ev[a]; int xi = eid[a];
        int p = a - 1;
        while (p >= 0 && (ev[p] < xv || (ev[p] == xv && eid[p] > xi))) {
            ev[p + 1] = ev[p]; eid[p + 1] = eid[p]; --p;
        }
        ev[p + 1] = xv; eid[p + 1] = xi;
    }

    if (krk == 0 && tid < TOPK)
        out_w[b * TOPK + tid] = __expf(ev[tid] - M) / S;

    // ---- gather the full 40KB row; all 10 loads in flight before stores ----
    const int id = eid[krk];                    // uniform across block
    const float4* src = reinterpret_cast<const float4*>(values + (size_t)id * LDV);
    float4*       dst = reinterpret_cast<float4*>(out_v + (size_t)bk * LDV);
    // LDV/4 = 2560 = 10 * 256
    float4 buf[10];
    #pragma unroll
    for (int i = 0; i < 10; ++i) buf[i] = src[tid + i * 256];
    #pragma unroll
    for (int i = 0; i < 10; ++i) dst[tid + i * 256] = buf[i];
}

extern "C" void kernel_launch(void* const* d_in, const int* in_sizes, int n_in,
                              void* d_out, int out_size, void* d_ws, size_t ws_size,
                              hipStream_t stream) {
    const float* q      = (const float*)d_in[0];
    const float* keys   = (const float*)d_in[1];
    const float* values = (const float*)d_in[2];

    const int B   = in_sizes[0] / DKD;                 // 32
    const int N   = in_sizes[1] / DKD;                 // 20000
    const int LDV = (int)((long long)in_sizes[2] / N); // 10240
    const int NTB = (N + 63) / 64;                     // 313

    float* out   = (float*)d_out;
    float* out_w = out;
    float* out_v = out + (size_t)B * TOPK;

    char* wsb = (char*)d_ws;
    size_t off = 0;
    float* pmg = (float*)(wsb + off); off += (size_t)B * NTB * sizeof(float);
    float* psg = (float*)(wsb + off); off += (size_t)B * NTB * sizeof(float);
    float* cvg = (float*)(wsb + off); off += (size_t)B * NTB * 8 * sizeof(float);
    int*   cig = (int*)(wsb + off);   off += (size_t)B * NTB * 8 * sizeof(int);

    score_part_kernel<<<NTB, 256, 0, stream>>>(q, keys, pmg, psg, cvg, cig, N, NTB);
    merge_gather_kernel<<<B * TOPK, 256, 0, stream>>>(
        pmg, psg, cvg, cig, q, keys, values, out_w, out_v, NTB, LDV);
}

// Round 15
// 40.318 us; speedup vs baseline: 8.3321x; 1.0631x over previous
//
#include <hip/hip_runtime.h>
#include <math.h>

// ---------------------------------------------------------------------------
// B=32 queries [B,512] fp32 vs N=20000 keys [N,512] fp32.
// scores = Q K^T / sqrt(512); softmax over N; top-8; gather values rows.
// Output = [B*8 weights f32] ++ [B*8 * 10240 values f32].
//
// R15 = R14 with K1 load-BALANCED: grid 250 blocks x 80 keys (20000=250x80,
// no tail; R14's 313x4 waves put 2 tiles on 226 of 1024 wave-slots -> ~57
// CUs streamed 2x the bytes -> K1 ran ~2x its balanced time). 5 tiles/block
// on 4 waves (wave 0 takes {0,4}; BW-bound so intra-block wave asymmetry is
// harmless). NTB=250<256 also collapses K2's merge to ONE round.
//  K1 score_part: balanced MFMA + per-row (m, sum-exp, top-8 of 80) partials.
//  K2 merge_gather: R14-proven (merge -> 4-wave parallel exact rescore ->
//     per-thread exact sort -> krk==0 weights; 10-deep pipelined gather).
// ---------------------------------------------------------------------------

#define TOPK 8
#define DKD 512
#define NEG  -1.0e30f
#define KPB  80          // keys per block in K1
#define TPB  5           // 16-key tiles per block

typedef __attribute__((ext_vector_type(8))) short short8;
typedef __attribute__((ext_vector_type(4))) float f32x4;

__device__ inline unsigned short f2bf(float x) {
    unsigned int u = __float_as_uint(x);
    u = (u + 0x7fffu + ((u >> 16) & 1u)) >> 16;   // RNE to bf16
    return (unsigned short)u;
}

// comparator everywhere: value desc, index asc (matches lax.top_k ties)
__device__ inline void wave_argmax(float& v, int& i) {
    #pragma unroll
    for (int off = 1; off < 64; off <<= 1) {
        float ov = __shfl_xor(v, off);
        int   oi = __shfl_xor(i, off);
        if (ov > v || (ov == v && oi < i)) { v = ov; i = oi; }
    }
}

// sorted-desc top-8 insert (strict > keeps earlier index on ties)
__device__ inline void top8_insert(float (&v)[8], int (&ji)[8], float x, int gi) {
    if (x > v[7]) {
        bool g[8];
        #pragma unroll
        for (int k = 0; k < 8; ++k) g[k] = (x > v[k]);
        #pragma unroll
        for (int k = 7; k >= 1; --k) {
            v[k]  = g[k] ? (g[k - 1] ? v[k - 1] : x)  : v[k];
            ji[k] = g[k] ? (g[k - 1] ? ji[k - 1] : gi) : ji[k];
        }
        v[0]  = g[0] ? x  : v[0];
        ji[0] = g[0] ? gi : ji[0];
    }
}

// ---- K1: balanced MFMA scores (80 keys/block) + per-row partials ----------
__global__ __launch_bounds__(256) void score_part_kernel(
    const float* __restrict__ q, const float* __restrict__ keys,
    float* __restrict__ pmg, float* __restrict__ psg,
    float* __restrict__ cvg, int* __restrict__ cig, int N, int NTB)
{
    const int tid  = threadIdx.x;
    const int lane = tid & 63;
    const int wid  = tid >> 6;
    const float scale = 0.04419417382415922f;   // 1/sqrt(512)

    __shared__ short qs[32][DKD + 8];   // bf16 q, +8 pad (2-way banks = free)
    __shared__ float S[32][KPB + 5];    // scores tile; stride 85 (gcd(85,32)=1)

    // ---- P0: q -> bf16 into LDS (64KB read, 1x per block) ----
    #pragma unroll
    for (int i = 0; i < 16; ++i) {
        const int idx = i * 256 + tid;          // 0..4095 float4s
        const int row = idx >> 7;               // 128 float4 per row
        const int c4  = idx & 127;
        float4 v = *reinterpret_cast<const float4*>(&q[row * DKD + c4 * 4]);
        ushort4 h;
        h.x = f2bf(v.x); h.y = f2bf(v.y); h.z = f2bf(v.z); h.w = f2bf(v.w);
        *reinterpret_cast<ushort4*>(&qs[row][c4 * 4]) = h;
    }
    __syncthreads();

    // ---- P1: 5 16-key tiles over 4 waves (wave 0 takes {0,4}) ----
    {
        const int col = lane & 15;
        const int kg  = lane >> 4;

        for (int t = wid; t < TPB; t += 4) {
            const int n0 = blockIdx.x * KPB + t * 16;

            f32x4 acc0 = {0.f, 0.f, 0.f, 0.f};
            f32x4 acc1 = {0.f, 0.f, 0.f, 0.f};

            int nrow = n0 + col;
            const bool valid = (nrow < N);
            if (!valid) nrow = N - 1;           // clamp loads
            const float* krow = keys + (size_t)nrow * DKD + kg * 8;
            const short* s0 = &qs[col][kg * 8];
            const short* s1 = &qs[col + 16][kg * 8];

            #pragma unroll 4
            for (int ks = 0; ks < 16; ++ks) {
                const int d = ks * 32;
                float4 ka = *reinterpret_cast<const float4*>(krow + d);
                float4 kb = *reinterpret_cast<const float4*>(krow + d + 4);
                short8 fh;
                fh[0] = (short)f2bf(ka.x); fh[1] = (short)f2bf(ka.y);
                fh[2] = (short)f2bf(ka.z); fh[3] = (short)f2bf(ka.w);
                fh[4] = (short)f2bf(kb.x); fh[5] = (short)f2bf(kb.y);
                fh[6] = (short)f2bf(kb.z); fh[7] = (short)f2bf(kb.w);
                short8 a0 = *reinterpret_cast<const short8*>(s0 + d);
                short8 a1 = *reinterpret_cast<const short8*>(s1 + d);
                acc0 = __builtin_amdgcn_mfma_f32_16x16x32_bf16(a0, fh, acc0, 0, 0, 0);
                acc1 = __builtin_amdgcn_mfma_f32_16x16x32_bf16(a1, fh, acc1, 0, 0, 0);
            }

            // D layout (m89-verified): col = lane&15, row = (lane>>4)*4 + reg
            #pragma unroll
            for (int j = 0; j < 4; ++j) {
                const int r = kg * 4 + j;
                S[r][t * 16 + col]      = valid ? acc0[j] * scale : NEG;
                S[r + 16][t * 16 + col] = valid ? acc1[j] * scale : NEG;
            }
        }
    }
    __syncthreads();

    // ---- P2: per-row partials: 8 threads/row x 10 cols each ----
    {
        const int r = tid >> 3;                 // row 0..31
        const int g = tid & 7;                  // 8-lane group position
        float m = NEG, s = 0.f;
        float v[8]; int ji[8];
        #pragma unroll
        for (int k = 0; k < 8; ++k) { v[k] = NEG; ji[k] = 0x7ffffffe; }

        #pragma unroll
        for (int e = 0; e < 10; ++e) {
            const int c  = g * 10 + e;
            const float x = S[r][c];
            const int  gi = blockIdx.x * KPB + c;
            if (x > -5e29f) {                   // skip invalid-key sentinels
                const float nm = fmaxf(m, x);
                s = s * __expf(m - nm) + __expf(x - nm);
                m = nm;
                top8_insert(v, ji, x, gi);
            }
        }

        // group (m,s) combine over 8 lanes
        #pragma unroll
        for (int off = 1; off < 8; off <<= 1) {
            float om = __shfl_xor(m, off), os = __shfl_xor(s, off);
            float M2 = fmaxf(m, om);
            s = s * __expf(m - M2) + os * __expf(om - M2);
            m = M2;
        }

        // group top-8 selection (8 rounds over 8 sorted lists)
        float sel_v[8]; int sel_i[8];
        #pragma unroll
        for (int rr = 0; rr < 8; ++rr) {
            float mv = v[0]; int mi = ji[0];
            #pragma unroll
            for (int off = 1; off < 8; off <<= 1) {
                float ov = __shfl_xor(mv, off);
                int   oi = __shfl_xor(mi, off);
                if (ov > mv || (ov == mv && oi < mi)) { mv = ov; mi = oi; }
            }
            if (v[0] == mv && ji[0] == mi) {    // I won: pop my head
                #pragma unroll
                for (int k = 0; k < 7; ++k) { v[k] = v[k + 1]; ji[k] = ji[k + 1]; }
                v[7] = NEG; ji[7] = 0x7ffffffe;
            }
            sel_v[rr] = mv; sel_i[rr] = mi;
        }

        if (g == 0) {
            const size_t base = (size_t)r * NTB + blockIdx.x;
            pmg[base] = m; psg[base] = s;
            #pragma unroll
            for (int k = 0; k < 8; ++k) {
                cvg[base * 8 + k] = sel_v[k];
                cig[base * 8 + k] = sel_i[k];
            }
        }
    }
}

// ---- K2: 256 blocks = one per output row: merge -> par. rescore -> gather -
__global__ __launch_bounds__(256) void merge_gather_kernel(
    const float* __restrict__ pmg, const float* __restrict__ psg,
    const float* __restrict__ cvg, const int* __restrict__ cig,
    const float* __restrict__ q, const float* __restrict__ keys,
    const float* __restrict__ values,
    float* __restrict__ out_w, float* __restrict__ out_v, int NTB, int LDV)
{
    const int bk   = blockIdx.x;                // output row 0..255
    const int b    = bk >> 3;                   // query row
    const int krk  = bk & 7;                    // rank within top-8
    const int tid  = threadIdx.x;
    const int lane = tid & 63;
    const int wid  = tid >> 6;
    const float scale = 0.04419417382415922f;

    __shared__ float lm[4], ls[4], lcv[4][TOPK];
    __shared__ int   lci[4][TOPK];
    __shared__ float s_exv[12];
    __shared__ int   s_sid[12];

    // ---- thread-local: one partial each (NTB=250 <= 256: single round) ----
    float m = NEG, s = 0.f;
    float v[8]; int ji[8];
    #pragma unroll
    for (int k = 0; k < 8; ++k) { v[k] = NEG; ji[k] = 0x7ffffffe; }

    for (int tb = tid; tb < NTB; tb += 256) {
        const size_t base = (size_t)b * NTB + tb;
        const float pm_t = pmg[base], ps_t = psg[base];
        const float M2 = fmaxf(m, pm_t);
        s = s * __expf(m - M2) + ps_t * __expf(pm_t - M2);
        m = M2;
        #pragma unroll
        for (int k = 0; k < 8; ++k) {
            top8_insert(v, ji, cvg[base * 8 + k], cig[base * 8 + k]);
        }
    }

    // ---- wave-level (m,s) combine ----
    #pragma unroll
    for (int off = 1; off < 64; off <<= 1) {
        float om = __shfl_xor(m, off), os = __shfl_xor(s, off);
        float M2 = fmaxf(m, om);
        s = s * __expf(m - M2) + os * __expf(om - M2);
        m = M2;
    }

    // ---- wave-level top-8 merge: 8 selection rounds ----
    float selv = 0.f; int seli = 0;
    #pragma unroll
    for (int r = 0; r < TOPK; ++r) {
        float mv = v[0]; int mi = ji[0];
        wave_argmax(mv, mi);
        if (v[0] == mv && ji[0] == mi) {       // I won: pop my head
            #pragma unroll
            for (int k = 0; k < TOPK - 1; ++k) { v[k] = v[k + 1]; ji[k] = ji[k + 1]; }
            v[TOPK - 1] = NEG; ji[TOPK - 1] = 0x7ffffffe;
        }
        if (lane == r) { selv = mv; seli = mi; }
    }

    if (lane == 0) { lm[wid] = m; ls[wid] = s; }
    if (lane < TOPK) { lcv[wid][lane] = selv; lci[wid][lane] = seli; }
    __syncthreads();

    // ---- cross-wave combine (ALL waves, redundant -> everyone has M,S) ----
    float M = lm[0], S = ls[0];
    #pragma unroll
    for (int cc = 1; cc < 4; ++cc) {
        float M2 = fmaxf(M, lm[cc]);
        S = S * __expf(M - M2) + ls[cc] * __expf(lm[cc] - M2);
        M = M2;
    }

    // ---- 32 candidates -> approx top-12 (ALL waves, identical result) ----
    {
        float vv = (lane < 32) ? lcv[lane >> 3][lane & 7] : NEG;
        int   ii = (lane < 32) ? lci[lane >> 3][lane & 7] : 0x7ffffffe;
        int   si = 0x7ffffffe;
        #pragma unroll
        for (int r = 0; r < 12; ++r) {
            float mv = vv; int mi = ii;
            wave_argmax(mv, mi);
            if (vv == mv && ii == mi) vv = NEG;
            if (lane == r) si = mi;
        }

        // ---- wave wid rescores candidates 3*wid .. 3*wid+2 (fp32 exact,
        //      identical FP order across the row's 8 blocks) ----
        float4 qa = *reinterpret_cast<const float4*>(q + (size_t)b * DKD + lane * 8);
        float4 qb = *reinterpret_cast<const float4*>(q + (size_t)b * DKD + lane * 8 + 4);
        #pragma unroll
        for (int t = 0; t < 3; ++t) {
            const int r = wid * 3 + t;
            const int cand = __shfl(si, r);
            const float* kr = keys + (size_t)cand * DKD + lane * 8;
            float4 k1 = *reinterpret_cast<const float4*>(kr);
            float4 k2 = *reinterpret_cast<const float4*>(kr + 4);
            float p = qa.x * k1.x + qa.y * k1.y + qa.z * k1.z + qa.w * k1.w
                    + qb.x * k2.x + qb.y * k2.y + qb.z * k2.z + qb.w * k2.w;
            #pragma unroll
            for (int off = 1; off < 64; off <<= 1) p += __shfl_xor(p, off);
            if (lane == 0) { s_exv[r] = p * scale; s_sid[r] = cand; }
        }
    }
    __syncthreads();

    // ---- per-thread exact sort of the 12 (value desc, index asc) ----
    float ev[12]; int eid[12];
    #pragma unroll
    for (int k = 0; k < 12; ++k) { ev[k] = s_exv[k]; eid[k] = s_sid[k]; }
    #pragma unroll
    for (int a = 1; a < 12; ++a) {
        float xv = ev[a]; int xi = eid[a];
        int p = a - 1;
        while (p >= 0 && (ev[p] < xv || (ev[p] == xv && eid[p] > xi))) {
            ev[p + 1] = ev[p]; eid[p + 1] = eid[p]; --p;
        }
        ev[p + 1] = xv; eid[p + 1] = xi;
    }

    if (krk == 0 && tid < TOPK)
        out_w[b * TOPK + tid] = __expf(ev[tid] - M) / S;

    // ---- gather the full 40KB row; all 10 loads in flight before stores ----
    const int id = eid[krk];                    // uniform across block
    const float4* src = reinterpret_cast<const float4*>(values + (size_t)id * LDV);
    float4*       dst = reinterpret_cast<float4*>(out_v + (size_t)bk * LDV);
    // LDV/4 = 2560 = 10 * 256
    float4 buf[10];
    #pragma unroll
    for (int i = 0; i < 10; ++i) buf[i] = src[tid + i * 256];
    #pragma unroll
    for (int i = 0; i < 10; ++i) dst[tid + i * 256] = buf[i];
}

extern "C" void kernel_launch(void* const* d_in, const int* in_sizes, int n_in,
                              void* d_out, int out_size, void* d_ws, size_t ws_size,
                              hipStream_t stream) {
    const float* q      = (const float*)d_in[0];
    const float* keys   = (const float*)d_in[1];
    const float* values = (const float*)d_in[2];

    const int B   = in_sizes[0] / DKD;                 // 32
    const int N   = in_sizes[1] / DKD;                 // 20000
    const int LDV = (int)((long long)in_sizes[2] / N); // 10240
    const int NTB = (N + KPB - 1) / KPB;               // 250

    float* out   = (float*)d_out;
    float* out_w = out;
    float* out_v = out + (size_t)B * TOPK;

    char* wsb = (char*)d_ws;
    size_t off = 0;
    float* pmg = (float*)(wsb + off); off += (size_t)B * NTB * sizeof(float);
    float* psg = (float*)(wsb + off); off += (size_t)B * NTB * sizeof(float);
    float* cvg = (float*)(wsb + off); off += (size_t)B * NTB * 8 * sizeof(float);
    int*   cig = (int*)(wsb + off);   off += (size_t)B * NTB * 8 * sizeof(int);

    score_part_kernel<<<NTB, 256, 0, stream>>>(q, keys, pmg, psg, cvg, cig, N, NTB);
    merge_gather_kernel<<<B * TOPK, 256, 0, stream>>>(
        pmg, psg, cvg, cig, q, keys, values, out_w, out_v, NTB, LDV);
}